// Round 14
// baseline (70.640 us; speedup 1.0000x reference)
//
#include <hip/hip_runtime.h>

#define NN 4096
#define FIN 256
#define CC 256
#define NH 8
#define NW32 (NN / 32)  // u32 words per adj row

typedef __attribute__((ext_vector_type(8))) short short8;
typedef __attribute__((ext_vector_type(4))) float f32x4;
typedef __attribute__((ext_vector_type(4))) unsigned int u32x4;

__device__ __forceinline__ unsigned cvtpk_bf16(float lo, float hi) {
  unsigned r;
  asm("v_cvt_pk_bf16_f32 %0, %1, %2" : "=v"(r) : "v"(lo), "v"(hi));
  return r;
}

__device__ __forceinline__ unsigned short bf16rn(float x) {
  unsigned int u = __builtin_bit_cast(unsigned int, x);
  u += 0x7fffu + ((u >> 16) & 1u);
  return (unsigned short)(u >> 16);
}

__device__ __forceinline__ void gl_lds16(const void* g, void* l) {
  __builtin_amdgcn_global_load_lds(
      (const __attribute__((address_space(1))) void*)g,
      (__attribute__((address_space(3))) void*)l, 16, 0, 0);
}

// ---------------- K1: fused {GEMM+epilogue | adj bitpack} by block range ---
// blocks [0,512): GEMM g=h@W -> swizzled gTs + spack + dtc.
// blocks [512, 512+2048): bitpack (one u32 word per thread, 8x int4 stream).
// adjb[i][w] bit e = adj[i][w*32+e]!=0.
// gTs: chunk-major SWIZZLED bf16 (16B unit at [jc][c][p], p = q ^ ((c>>1)&3)).
// spack[h][n] = (e^s_src, e^{0.2 s_src}, 0, 0).
// dtc[h][jc][plane][32] = (e^sd, e^{0.2 sd})  (per-head contiguous over jc).
#define GROWS 8
#define GEMM_BLKS (NN / GROWS)                  // 512
#define BP_BLKS (NN * NW32 / 256)               // 2048
__global__ __launch_bounds__(256) void k_gemm(
    const float* __restrict__ h, const float* __restrict__ W,
    const float* __restrict__ a, const int* __restrict__ adj,
    unsigned int* __restrict__ adjb, unsigned short* __restrict__ gTs,
    float4* __restrict__ spack, float* __restrict__ dtc) {
  __shared__ float hs[GROWS][FIN];
  const int t = threadIdx.x;
  const int bx = blockIdx.x;

  if (bx >= GEMM_BLKS) {
    const int wid = (bx - GEMM_BLKS) * 256 + t;  // word index
    const int row = wid >> 7, wd = wid & 127;
    const int* src = adj + (size_t)row * NN + wd * 32;
    int4 v[8];
#pragma unroll
    for (int s = 0; s < 8; ++s) v[s] = *(const int4*)&src[s * 4];
    unsigned int bits = 0;
#pragma unroll
    for (int s = 0; s < 8; ++s) {
      bits |= (v[s].x ? 1u : 0u) << (s * 4 + 0);
      bits |= (v[s].y ? 1u : 0u) << (s * 4 + 1);
      bits |= (v[s].z ? 1u : 0u) << (s * 4 + 2);
      bits |= (v[s].w ? 1u : 0u) << (s * 4 + 3);
    }
    adjb[(size_t)row * NW32 + wd] = bits;
    return;
  }

  // ---- GEMM path ----
  const int r0 = bx * GROWS;
#pragma unroll
  for (int idx = t; idx < GROWS * FIN / 4; idx += 256) {
    const int r = idx >> 6, c4 = idx & 63;
    *(float4*)&hs[r][c4 * 4] =
        *(const float4*)&h[(size_t)(r0 + r) * FIN + c4 * 4];
  }
  __syncthreads();
  const int c = t;
  float acc[GROWS];
#pragma unroll
  for (int r = 0; r < GROWS; ++r) acc[r] = 0.f;
  for (int k = 0; k < FIN; k += 4) {
    const float w0 = W[(size_t)(k + 0) * CC + c];
    const float w1 = W[(size_t)(k + 1) * CC + c];
    const float w2 = W[(size_t)(k + 2) * CC + c];
    const float w3 = W[(size_t)(k + 3) * CC + c];
#pragma unroll
    for (int r = 0; r < GROWS; ++r) {
      const float4 hv = *(const float4*)&hs[r][k];
      acc[r] += hv.x * w0 + hv.y * w1 + hv.z * w2 + hv.w * w3;
    }
  }
  const int f = c & 31, hh = c >> 5;
  const float aS = a[f], aD = a[32 + f];
  unsigned short gu[GROWS];
#pragma unroll
  for (int r = 0; r < GROWS; ++r) {
    float ps = acc[r] * aS, pd = acc[r] * aD;
#pragma unroll
    for (int m = 1; m < 32; m <<= 1) {
      ps += __shfl_xor(ps, m, 64);
      pd += __shfl_xor(pd, m, 64);
    }
    if (f == 0) {
      const int n = r0 + r;
      spack[(size_t)hh * NN + n] =
          make_float4(__expf(ps), __expf(0.2f * ps), 0.f, 0.f);
      float* dc = dtc + ((size_t)hh * (NN / 32) + (n >> 5)) * 64 + (n & 31);
      dc[0] = __expf(pd);
      dc[32] = __expf(0.2f * pd);
    }
    gu[r] = bf16rn(acc[r]);
  }
  uint4 gv;
  gv.x = (unsigned)gu[0] | ((unsigned)gu[1] << 16);
  gv.y = (unsigned)gu[2] | ((unsigned)gu[3] << 16);
  gv.z = (unsigned)gu[4] | ((unsigned)gu[5] << 16);
  gv.w = (unsigned)gu[6] | ((unsigned)gu[7] << 16);
  const int jc = r0 >> 5, qq = (r0 >> 3) & 3;
  const int p = qq ^ ((c >> 1) & 3);
  *(uint4*)(gTs + ((size_t)jc * 1024 + c * 4 + p) * 8) = gv;
}

// ---------------- K2: whole-split-staged fused masked-softmax + MFMA PV ----
// Block = 256 i x 1 head; 4 waves = 4 i-quarters (64 i each, it=0..3).
// Stage 512 j at once (gt 32KB swizzled + dt 4KB), ONE barrier, then pure
// register/LDS compute for 16 chunks — no per-chunk lockstep.
// e^leaky(ss+sd) = max(e^ss*e^sd, e^{0.2ss}*e^{0.2sd})  (exact identity).
__global__ __launch_bounds__(256, 3) void k_attn(
    const unsigned int* __restrict__ adjb, const unsigned short* __restrict__ gTs,
    const float4* __restrict__ spack, const float* __restrict__ dtc,
    float* __restrict__ acc_ws, float* __restrict__ l_ws,
    float* __restrict__ out, const int splits, const int direct) {
  __shared__ unsigned short gt_lds[2048 * 8];  // 32 KB: 16 ch x 128 units x 8
  __shared__ float dt_lds[16][2][32];          // 4 KB

  const int lane = threadIdx.x & 63;
  const int w = threadIdx.x >> 6;
  const int il = lane & 15, q = lane >> 4;
  const int bx = blockIdx.x;
  const int sp = bx & (splits - 1);
  const int rest = bx / splits;
  const int hh = rest & 7;
  const int ib = rest >> 3;
  const int i0w = ib * 256 + w * 64;  // this wave's 64 i-rows
  const int jrange = NN / splits, j0b = sp * jrange;
  const int c0 = j0b >> 5;

  // hoisted i-side scalars (4 it)
  float e1v[4], e2v[4];
#pragma unroll
  for (int it = 0; it < 4; ++it) {
    const float4 v = spack[(size_t)hh * NN + i0w + it * 16 + il];
    e1v[it] = v.x; e2v[it] = v.y;
  }

  f32x4 acc[4][2];
  f32x4 lac[4];
#pragma unroll
  for (int it = 0; it < 4; ++it) {
#pragma unroll
    for (int r = 0; r < 4; ++r) lac[it][r] = 0.f;
#pragma unroll
    for (int ft = 0; ft < 2; ++ft)
#pragma unroll
      for (int r = 0; r < 4; ++r) acc[it][ft][r] = 0.f;
  }

  const short8 ones = {(short)0x3F80, (short)0x3F80, (short)0x3F80,
                       (short)0x3F80, (short)0x3F80, (short)0x3F80,
                       (short)0x3F80, (short)0x3F80};

  // bitpacked adj row pointers (u64 per 64 j), one per it-tile
  const unsigned long long* ab[4];
#pragma unroll
  for (int it = 0; it < 4; ++it)
    ab[it] = (const unsigned long long*)(adjb +
                                         (size_t)(i0w + it * 16 + il) * NW32) +
             (j0b >> 6);

  const int sh = q * 8;
  const int pswz = q ^ ((il >> 1) & 3);

  // ---- stage one 512-j super-chunk (16 jc): gt 32KB + dt 4KB ----
  auto stage = [&](int s) {
    const int jc0 = c0 + s * 16;
#pragma unroll
    for (int p = 0; p < 8; ++p) {
      const int base = p * 256 + w * 64;  // wave-uniform dest unit
      const int g = base + lane;
      const unsigned short* src =
          gTs + (((size_t)(jc0 + (g >> 7)) << 10) + hh * 128 + (g & 127)) * 8;
      gl_lds16(src, (char*)gt_lds + (size_t)base * 16);
    }
    {
      const int base = w * 64;
      const float* dsrc =
          dtc + ((size_t)hh * (NN / 32) + jc0) * 64 + (base + lane) * 4;
      gl_lds16(dsrc, (char*)&dt_lds[0][0][0] + (size_t)base * 16);
    }
  };

  const int nstg = jrange >> 9;  // 512 j per stage
  for (int s = 0; s < nstg; ++s) {
    __syncthreads();  // previous stage's readers done (no-op first iter)
    stage(s);
    unsigned long long pb[4];
#pragma unroll
    for (int it = 0; it < 4; ++it) pb[it] = ab[it][s * 8];
    __syncthreads();  // staging complete

    for (int cp = 0; cp < 8; ++cp) {
      unsigned int bl[4][2];
#pragma unroll
      for (int it = 0; it < 4; ++it) {
        bl[it][0] = (unsigned int)pb[it];
        bl[it][1] = (unsigned int)(pb[it] >> 32);
      }
      if (cp + 1 < 8) {
#pragma unroll
        for (int it = 0; it < 4; ++it) pb[it] = ab[it][s * 8 + cp + 1];
      }
#pragma unroll
      for (int sub = 0; sub < 2; ++sub) {
        const int ch = cp * 2 + sub;
        float e1j[8], e2j[8];
        *(float4*)&e1j[0] = *(const float4*)&dt_lds[ch][0][q * 8];
        *(float4*)&e1j[4] = *(const float4*)&dt_lds[ch][0][q * 8 + 4];
        *(float4*)&e2j[0] = *(const float4*)&dt_lds[ch][1][q * 8];
        *(float4*)&e2j[4] = *(const float4*)&dt_lds[ch][1][q * 8 + 4];
        const int u0 = ch * 128 + il * 4 + pswz;
        const short8 b0 = *(const short8*)&gt_lds[(size_t)u0 * 8];
        const short8 b1 = *(const short8*)&gt_lds[(size_t)(u0 + 64) * 8];
#pragma unroll
        for (int it = 0; it < 4; ++it) {
          const unsigned int bits = bl[it][sub];
          const float ei1 = e1v[it], ei2 = e2v[it];
          float wv[8];
#pragma unroll
          for (int e = 0; e < 8; ++e)
            wv[e] = fmaxf(ei1 * e1j[e], ei2 * e2j[e]) *
                    (float)((bits >> (sh + e)) & 1u);
          u32x4 uu;
#pragma unroll
          for (int m = 0; m < 4; ++m)
            uu[m] = cvtpk_bf16(wv[2 * m], wv[2 * m + 1]);
          const short8 afr = __builtin_bit_cast(short8, uu);
          acc[it][0] = __builtin_amdgcn_mfma_f32_16x16x32_bf16(
              afr, b0, acc[it][0], 0, 0, 0);
          acc[it][1] = __builtin_amdgcn_mfma_f32_16x16x32_bf16(
              afr, b1, acc[it][1], 0, 0, 0);
          lac[it] = __builtin_amdgcn_mfma_f32_16x16x32_bf16(
              afr, ones, lac[it], 0, 0, 0);
        }
      }
    }
  }

  if (direct) {
#pragma unroll
    for (int it = 0; it < 4; ++it)
#pragma unroll
      for (int r = 0; r < 4; ++r) {
        const float inv = 1.f / lac[it][r];
        const size_t irow = i0w + it * 16 + q * 4 + r;
#pragma unroll
        for (int ft = 0; ft < 2; ++ft)
          out[irow * CC + hh * 32 + ft * 16 + il] = acc[it][ft][r] * inv;
      }
  } else {
#pragma unroll
    for (int it = 0; it < 4; ++it)
#pragma unroll
      for (int r = 0; r < 4; ++r) {
        const size_t irow = i0w + it * 16 + q * 4 + r;
        if (il == 0)
          l_ws[((size_t)sp * NH + hh) * NN + irow] = lac[it][r];
#pragma unroll
        for (int ft = 0; ft < 2; ++ft)
          acc_ws[((size_t)sp * NN + irow) * CC + hh * 32 + ft * 16 + il] =
              acc[it][ft][r];
      }
  }
}

// ---------------- K3: combine split partials ----------------
__global__ __launch_bounds__(256) void k_combine(
    const float* __restrict__ acc_ws, const float* __restrict__ l_ws,
    float* __restrict__ out, const int splits) {
  const int idx = blockIdx.x * 256 + threadIdx.x;  // float4 index
  const int row = idx >> 6, c4 = idx & 63;
  const int hh = c4 >> 3;
  float ax = 0.f, ay = 0.f, az = 0.f, aw = 0.f, l = 0.f;
  for (int s = 0; s < splits; ++s) {
    const float4 v =
        *(const float4*)&acc_ws[((size_t)s * NN + row) * CC + c4 * 4];
    ax += v.x; ay += v.y; az += v.z; aw += v.w;
    l += l_ws[((size_t)s * NH + hh) * NN + row];
  }
  const float inv = 1.f / l;
  *(float4*)&out[(size_t)row * CC + c4 * 4] =
      make_float4(ax * inv, ay * inv, az * inv, aw * inv);
}

extern "C" void kernel_launch(void* const* d_in, const int* in_sizes, int n_in,
                              void* d_out, int out_size, void* d_ws,
                              size_t ws_size, hipStream_t stream) {
  (void)in_sizes; (void)n_in; (void)out_size;
  const float* h = (const float*)d_in[0];
  const int* adj = (const int*)d_in[1];
  const float* W = (const float*)d_in[2];
  const float* a = (const float*)d_in[3];
  float* out = (float*)d_out;
  char* ws = (char*)d_ws;

  unsigned short* gTs = (unsigned short*)ws;               // 2 MB (swizzled)
  float4* spack = (float4*)(ws + (size_t)NN * CC * 2);     // 512 KB
  float* dtc = (float*)(spack + (size_t)NH * NN);          // 256 KB
  unsigned int* adjb =
      (unsigned int*)(dtc + (size_t)NH * (NN / 32) * 64);  // 2 MB
  char* after = (char*)(adjb + (size_t)NN * NW32);
  const size_t base = (size_t)(after - ws);
  const size_t per_split = (size_t)NN * CC * 4 + (size_t)NH * NN * 4;

  int splits = 1;
  if (ws_size >= base + 8 * per_split) splits = 8;
  else if (ws_size >= base + 4 * per_split) splits = 4;
  else if (ws_size >= base + 2 * per_split) splits = 2;

  k_gemm<<<GEMM_BLKS + BP_BLKS, 256, 0, stream>>>(h, W, a, adj, adjb, gTs,
                                                  spack, dtc);

  const int nblk = (NN / 256) * NH * splits;
  if (splits == 1) {
    k_attn<<<nblk, 256, 0, stream>>>(adjb, gTs, spack, dtc, nullptr, nullptr,
                                     out, 1, 1);
  } else {
    float* acc_ws = (float*)after;
    float* l_ws = acc_ws + (size_t)splits * NN * CC;
    k_attn<<<nblk, 256, 0, stream>>>(adjb, gTs, spack, dtc, acc_ws, l_ws, out,
                                     splits, 0);
    k_combine<<<NN * CC / 4 / 256, 256, 0, stream>>>(acc_ws, l_ws, out,
                                                     splits);
  }
}